// Round 23
// baseline (23.010 us; speedup 1.0000x reference)
//
#include <hip/hip_runtime.h>
#include <math.h>

// ChamferLoss via matrix cores — v_mfma_f32_32x32x16_f16 (K=16), PACKED:
// A-fragment lanes 0..31 (k=0..7)  = rows of tile 2T   (emb in e=0..4)
// A-fragment lanes 32..63 (k=8..15)= rows of tile 2T+1 (emb in e=0..4)
// B-frag bfLO: k=0..4 = (x,y,z,-|b|^2/2,1), k>=8 zero  -> C = tile2T   x col
// B-frag bfHI: k=8..12 = same, k<8 zero               -> C = tile2T+1 x col
// ONE full-width ds_read_b128 feeds 4 MFMAs (2 row-tiles x 2 col-tiles).
// C[i][j] = a.b - (|a|^2+|b|^2)/2 = -dist^2/2 ; min dist^2 = -2 max C.
//
// R23: WAVE-STAGGER experiment. Post-barrier, all 8 waves sweep the same
// tile order -> their 4-MFMA bursts collide at the matrix pipe in the
// same cycle windows (convoy). Stagger start tile by 4*wid (max commutes,
// wrap-around covers all tiles; wrap also replaces the pad prefetch).
// Zero extra instructions.

typedef _Float16 half8 __attribute__((ext_vector_type(8)));
typedef float floatx16 __attribute__((ext_vector_type(16)));

constexpr int B_ = 64;
constexpr int N_ = 2048;
constexpr int NT = N_ / 32;        // 64 row-tiles
constexpr int NPAIR = NT / 2;      // 32 packed tile-pairs
constexpr int BLOCK = 512;         // 8 waves
constexpr int WPB = 8;
constexpr int BFRAGS = 2;          // col-tiles per wave
constexpr int IBLK = NT / (WPB * BFRAGS);   // 4 blocks along col-tile axis
constexpr int NBLK = IBLK * B_ * 2;         // 512 partials
constexpr int RBLOCK = 256;

__global__ __launch_bounds__(BLOCK, 2) void chamfer_mfma_kernel(
    const float* __restrict__ p, const float* __restrict__ q,
    float* __restrict__ partials)
{
    __shared__ half8 Aarr[N_];            // 32 KB: Aarr[j] = emb(row j)
    __shared__ float wsum[WPB];

    const int dir = blockIdx.z;            // 0: A=q,B=p ; 1: A=p,B=q
    const int b   = blockIdx.y;
    const float4* rowsA = (const float4*)((dir == 0 ? q : p) + (size_t)b * N_ * 4);
    const float4* colsB = (const float4*)((dir == 0 ? p : q) + (size_t)b * N_ * 4);

    // Build the A-embedding table: Aarr[j] = (x,y,z,1,-|a|^2/2,0,0,0).
    for (int j = threadIdx.x; j < N_; j += BLOCK) {
        float4 v = rowsA[j];
        _Float16 x = (_Float16)v.y, y = (_Float16)v.z, z = (_Float16)v.w;
        float xf = (float)x, yf = (float)y, zf = (float)z;
        float sq = fmaf(xf, xf, fmaf(yf, yf, zf * zf));
        half8 lo;
        lo[0] = x; lo[1] = y; lo[2] = z; lo[3] = (_Float16)1.0f;
        lo[4] = (_Float16)(-0.5f * sq);
        lo[5] = (_Float16)0.0f; lo[6] = (_Float16)0.0f; lo[7] = (_Float16)0.0f;
        Aarr[j] = lo;
    }

    // Per-wave B fragments: col-tiles 2W, 2W+1; each as LO (k=0..7 lanes)
    // and HI (k=8..15 lanes) variants.
    const int lane = threadIdx.x & 63;
    const int wid  = threadIdx.x >> 6;
    const int W    = blockIdx.x * WPB + wid;
    half8 bfLO[BFRAGS], bfHI[BFRAGS];
#pragma unroll
    for (int t = 0; t < BFRAGS; ++t) {
        float4 v = colsB[(W * BFRAGS + t) * 32 + (lane & 31)];
        _Float16 x = (_Float16)v.y, y = (_Float16)v.z, z = (_Float16)v.w;
        float xf = (float)x, yf = (float)y, zf = (float)z;
        float sq = fmaf(xf, xf, fmaf(yf, yf, zf * zf));
#pragma unroll
        for (int e = 0; e < 8; ++e) { bfLO[t][e] = (_Float16)0.0f; bfHI[t][e] = (_Float16)0.0f; }
        if (lane < 32) {
            bfLO[t][0] = x; bfLO[t][1] = y; bfLO[t][2] = z;
            bfLO[t][3] = (_Float16)(-0.5f * sq);
            bfLO[t][4] = (_Float16)1.0f;
        } else {
            bfHI[t][0] = x; bfHI[t][1] = y; bfHI[t][2] = z;
            bfHI[t][3] = (_Float16)(-0.5f * sq);
            bfHI[t][4] = (_Float16)1.0f;
        }
    }
    __syncthreads();

    floatx16 zero;
#pragma unroll
    for (int i = 0; i < 16; ++i) zero[i] = 0.0f;

    floatx16 accv0, accv1;
#pragma unroll
    for (int i = 0; i < 16; ++i) { accv0[i] = -3.4e38f; accv1[i] = -3.4e38f; }

    // Staggered pipelined sweep: wave w starts at tile-pair 4*w; index
    // wraps mod 32 (max commutes -> coverage identical). Branch-free
    // prefetch via the wrap (no pad tile needed).
    const int woff = wid * 4;
    half8 af = Aarr[(woff & 31) * 64 + lane];
#pragma unroll 1
    for (int T = 0; T < NPAIR; ++T) {
        const int Tn = (T + 1 + woff) & 31;
        half8 afn = Aarr[Tn * 64 + lane];        // branch-free prefetch
        __builtin_amdgcn_s_setprio(1);
        floatx16 Ca0 = __builtin_amdgcn_mfma_f32_32x32x16_f16(af, bfLO[0], zero, 0, 0, 0);
        floatx16 Cb0 = __builtin_amdgcn_mfma_f32_32x32x16_f16(af, bfHI[0], zero, 0, 0, 0);
        floatx16 Ca1 = __builtin_amdgcn_mfma_f32_32x32x16_f16(af, bfLO[1], zero, 0, 0, 0);
        floatx16 Cb1 = __builtin_amdgcn_mfma_f32_32x32x16_f16(af, bfHI[1], zero, 0, 0, 0);
        __builtin_amdgcn_s_setprio(0);
#pragma unroll
        for (int i = 0; i < 16; ++i)
            accv0[i] = fmaxf(fmaxf(Ca0[i], Cb0[i]), accv0[i]);
#pragma unroll
        for (int i = 0; i < 16; ++i)
            accv1[i] = fmaxf(fmaxf(Ca1[i], Cb1[i]), accv1[i]);
        af = afn;
    }

    // Reduce the two 16-element accumulators to scalars (once per wave).
    float cmx0 = accv0[0], cmx1 = accv1[0];
#pragma unroll
    for (int i = 1; i < 16; ++i) {
        cmx0 = fmaxf(cmx0, accv0[i]);
        cmx1 = fmaxf(cmx1, accv1[i]);
    }

    // Combine the two lane-halves (each holds half the rows per column).
    cmx0 = fmaxf(cmx0, __shfl_xor(cmx0, 32, 64));
    cmx1 = fmaxf(cmx1, __shfl_xor(cmx1, 32, 64));

    float local = sqrtf(fmaxf(-2.0f * cmx0, 0.0f) + 1e-16f)
                + sqrtf(fmaxf(-2.0f * cmx1, 0.0f) + 1e-16f);

#pragma unroll
    for (int off = 32; off > 0; off >>= 1)
        local += __shfl_xor(local, off, 64);

    if (lane == 0) wsum[wid] = local;
    __syncthreads();
    if (threadIdx.x == 0) {
        float s = 0.0f;
#pragma unroll
        for (int w = 0; w < WPB; ++w) s += wsum[w];
        // 0.5 chamfer factor * 0.5 lane-dup; plain store, no init needed.
        partials[(blockIdx.z * B_ + blockIdx.y) * IBLK + blockIdx.x] = 0.25f * s;
    }
}

__global__ __launch_bounds__(RBLOCK) void chamfer_reduce_kernel(
    const float* __restrict__ partials, float* __restrict__ out)
{
    float v = partials[threadIdx.x] + partials[threadIdx.x + RBLOCK];
#pragma unroll
    for (int off = 32; off > 0; off >>= 1)
        v += __shfl_xor(v, off, 64);

    __shared__ float wsum[RBLOCK / 64];
    if ((threadIdx.x & 63) == 0) wsum[threadIdx.x >> 6] = v;
    __syncthreads();
    if (threadIdx.x == 0) {
        float s = 0.0f;
#pragma unroll
        for (int w = 0; w < RBLOCK / 64; ++w) s += wsum[w];
        out[0] = s;
    }
}

extern "C" void kernel_launch(void* const* d_in, const int* in_sizes, int n_in,
                              void* d_out, int out_size, void* d_ws, size_t ws_size,
                              hipStream_t stream) {
    const float* p = (const float*)d_in[0];
    const float* q = (const float*)d_in[1];
    float* out = (float*)d_out;
    float* partials = (float*)d_ws;

    dim3 grid(IBLK, B_, 2);                 // 4 x 64 x 2 = 512 blocks
    chamfer_mfma_kernel<<<grid, BLOCK, 0, stream>>>(p, q, partials);
    chamfer_reduce_kernel<<<1, RBLOCK, 0, stream>>>(partials, out);
}

// Round 24
// 22.451 us; speedup vs baseline: 1.0249x; 1.0249x over previous
//
#include <hip/hip_runtime.h>
#include <math.h>

// ChamferLoss via matrix cores — v_mfma_f32_32x32x16_f16 (K=16), PACKED:
// A-fragment lanes 0..31 (k=0..7)  = rows of tile 2T   (emb in e=0..4)
// A-fragment lanes 32..63 (k=8..15)= rows of tile 2T+1 (emb in e=0..4)
// B-frag bfLO: k=0..4 = (x,y,z,-|b|^2/2,1), k>=8 zero  -> C = tile2T   x col
// B-frag bfHI: k=8..12 = same, k<8 zero               -> C = tile2T+1 x col
// ONE full-width ds_read_b128 feeds 4 MFMAs (2 row-tiles x 2 col-tiles).
// C[i][j] = a.b - (|a|^2+|b|^2)/2 = -dist^2/2 ; min dist^2 = -2 max C.
//
// R24: VGPR-PINNING experiment. All profiled variants show VGPR_Count
// 28-44 + ~115 VALU instr/iter (static ~64): the compiler AGPR-allocates
// the MFMA C-tiles and launders each element via v_accvgpr_read before
// the fold. Empty asm with "+v" constraints pins C (and accv) to arch
// VGPRs — zero instructions if the allocator coalesces the MFMA dst
// (legal on gfx950 unified RF), deleting the laundering. The MFMA stays
// a builtin so the compiler keeps hazard bookkeeping (R9 lesson).

typedef _Float16 half8 __attribute__((ext_vector_type(8)));
typedef float floatx16 __attribute__((ext_vector_type(16)));

constexpr int B_ = 64;
constexpr int N_ = 2048;
constexpr int NT = N_ / 32;        // 64 row-tiles
constexpr int NPAIR = NT / 2;      // 32 packed tile-pairs
constexpr int BLOCK = 512;         // 8 waves
constexpr int WPB = 8;
constexpr int BFRAGS = 2;          // col-tiles per wave
constexpr int IBLK = NT / (WPB * BFRAGS);   // 4 blocks along col-tile axis
constexpr int NBLK = IBLK * B_ * 2;         // 512 partials
constexpr int RBLOCK = 256;

__global__ __launch_bounds__(BLOCK, 2) void chamfer_mfma_kernel(
    const float* __restrict__ p, const float* __restrict__ q,
    float* __restrict__ partials)
{
    __shared__ half8 Aarr[N_ + 64];       // 33 KB: +1 pad tile for prefetch
    __shared__ float wsum[WPB];

    const int dir = blockIdx.z;            // 0: A=q,B=p ; 1: A=p,B=q
    const int b   = blockIdx.y;
    const float4* rowsA = (const float4*)((dir == 0 ? q : p) + (size_t)b * N_ * 4);
    const float4* colsB = (const float4*)((dir == 0 ? p : q) + (size_t)b * N_ * 4);

    // Build the A-embedding table: Aarr[j] = (x,y,z,1,-|a|^2/2,0,0,0).
    for (int j = threadIdx.x; j < N_; j += BLOCK) {
        float4 v = rowsA[j];
        _Float16 x = (_Float16)v.y, y = (_Float16)v.z, z = (_Float16)v.w;
        float xf = (float)x, yf = (float)y, zf = (float)z;
        float sq = fmaf(xf, xf, fmaf(yf, yf, zf * zf));
        half8 lo;
        lo[0] = x; lo[1] = y; lo[2] = z; lo[3] = (_Float16)1.0f;
        lo[4] = (_Float16)(-0.5f * sq);
        lo[5] = (_Float16)0.0f; lo[6] = (_Float16)0.0f; lo[7] = (_Float16)0.0f;
        Aarr[j] = lo;
    }

    // Per-wave B fragments: col-tiles 2W, 2W+1; each as LO (k=0..7 lanes)
    // and HI (k=8..15 lanes) variants.
    const int lane = threadIdx.x & 63;
    const int wid  = threadIdx.x >> 6;
    const int W    = blockIdx.x * WPB + wid;
    half8 bfLO[BFRAGS], bfHI[BFRAGS];
#pragma unroll
    for (int t = 0; t < BFRAGS; ++t) {
        float4 v = colsB[(W * BFRAGS + t) * 32 + (lane & 31)];
        _Float16 x = (_Float16)v.y, y = (_Float16)v.z, z = (_Float16)v.w;
        float xf = (float)x, yf = (float)y, zf = (float)z;
        float sq = fmaf(xf, xf, fmaf(yf, yf, zf * zf));
#pragma unroll
        for (int e = 0; e < 8; ++e) { bfLO[t][e] = (_Float16)0.0f; bfHI[t][e] = (_Float16)0.0f; }
        if (lane < 32) {
            bfLO[t][0] = x; bfLO[t][1] = y; bfLO[t][2] = z;
            bfLO[t][3] = (_Float16)(-0.5f * sq);
            bfLO[t][4] = (_Float16)1.0f;
        } else {
            bfHI[t][0] = x; bfHI[t][1] = y; bfHI[t][2] = z;
            bfHI[t][3] = (_Float16)(-0.5f * sq);
            bfHI[t][4] = (_Float16)1.0f;
        }
    }
    __syncthreads();

    floatx16 zero;
#pragma unroll
    for (int i = 0; i < 16; ++i) zero[i] = 0.0f;

    floatx16 accv0, accv1;
#pragma unroll
    for (int i = 0; i < 16; ++i) { accv0[i] = -3.4e38f; accv1[i] = -3.4e38f; }

    // Pipelined sweep: branch-free af prefetch (pad tile read at T=31,
    // never folded); 4-MFMA cluster at raised priority; C-tiles and accv
    // pinned to arch VGPRs via empty "+v" asm (no instructions emitted).
    half8 af = Aarr[lane];
#pragma unroll 1
    for (int T = 0; T < NPAIR; ++T) {
        half8 afn = Aarr[(T + 1) * 64 + lane];   // branch-free prefetch
        __builtin_amdgcn_s_setprio(1);
        floatx16 Ca0 = __builtin_amdgcn_mfma_f32_32x32x16_f16(af, bfLO[0], zero, 0, 0, 0);
        floatx16 Cb0 = __builtin_amdgcn_mfma_f32_32x32x16_f16(af, bfHI[0], zero, 0, 0, 0);
        floatx16 Ca1 = __builtin_amdgcn_mfma_f32_32x32x16_f16(af, bfLO[1], zero, 0, 0, 0);
        floatx16 Cb1 = __builtin_amdgcn_mfma_f32_32x32x16_f16(af, bfHI[1], zero, 0, 0, 0);
        __builtin_amdgcn_s_setprio(0);
        // Pin MFMA results to arch VGPRs (regclass constraint only).
        asm("" : "+v"(Ca0), "+v"(Cb0), "+v"(Ca1), "+v"(Cb1));
#pragma unroll
        for (int i = 0; i < 16; ++i)
            accv0[i] = fmaxf(fmaxf(Ca0[i], Cb0[i]), accv0[i]);
#pragma unroll
        for (int i = 0; i < 16; ++i)
            accv1[i] = fmaxf(fmaxf(Ca1[i], Cb1[i]), accv1[i]);
        // Keep the loop-carried accumulators in arch VGPRs too.
        asm("" : "+v"(accv0), "+v"(accv1));
        af = afn;
    }

    // Reduce the two 16-element accumulators to scalars (once per wave).
    float cmx0 = accv0[0], cmx1 = accv1[0];
#pragma unroll
    for (int i = 1; i < 16; ++i) {
        cmx0 = fmaxf(cmx0, accv0[i]);
        cmx1 = fmaxf(cmx1, accv1[i]);
    }

    // Combine the two lane-halves (each holds half the rows per column).
    cmx0 = fmaxf(cmx0, __shfl_xor(cmx0, 32, 64));
    cmx1 = fmaxf(cmx1, __shfl_xor(cmx1, 32, 64));

    float local = sqrtf(fmaxf(-2.0f * cmx0, 0.0f) + 1e-16f)
                + sqrtf(fmaxf(-2.0f * cmx1, 0.0f) + 1e-16f);

#pragma unroll
    for (int off = 32; off > 0; off >>= 1)
        local += __shfl_xor(local, off, 64);

    if (lane == 0) wsum[wid] = local;
    __syncthreads();
    if (threadIdx.x == 0) {
        float s = 0.0f;
#pragma unroll
        for (int w = 0; w < WPB; ++w) s += wsum[w];
        // 0.5 chamfer factor * 0.5 lane-dup; plain store, no init needed.
        partials[(blockIdx.z * B_ + blockIdx.y) * IBLK + blockIdx.x] = 0.25f * s;
    }
}

__global__ __launch_bounds__(RBLOCK) void chamfer_reduce_kernel(
    const float* __restrict__ partials, float* __restrict__ out)
{
    float v = partials[threadIdx.x] + partials[threadIdx.x + RBLOCK];
#pragma unroll
    for (int off = 32; off > 0; off >>= 1)
        v += __shfl_xor(v, off, 64);

    __shared__ float wsum[RBLOCK / 64];
    if ((threadIdx.x & 63) == 0) wsum[threadIdx.x >> 6] = v;
    __syncthreads();
    if (threadIdx.x == 0) {
        float s = 0.0f;
#pragma unroll
        for (int w = 0; w < RBLOCK / 64; ++w) s += wsum[w];
        out[0] = s;
    }
}

extern "C" void kernel_launch(void* const* d_in, const int* in_sizes, int n_in,
                              void* d_out, int out_size, void* d_ws, size_t ws_size,
                              hipStream_t stream) {
    const float* p = (const float*)d_in[0];
    const float* q = (const float*)d_in[1];
    float* out = (float*)d_out;
    float* partials = (float*)d_ws;

    dim3 grid(IBLK, B_, 2);                 // 4 x 64 x 2 = 512 blocks
    chamfer_mfma_kernel<<<grid, BLOCK, 0, stream>>>(p, q, partials);
    chamfer_reduce_kernel<<<1, RBLOCK, 0, stream>>>(partials, out);
}

// Round 25
// 22.095 us; speedup vs baseline: 1.0414x; 1.0161x over previous
//
#include <hip/hip_runtime.h>
#include <math.h>

// ChamferLoss via matrix cores — v_mfma_f32_32x32x16_f16 (K=16), PACKED:
// A-fragment lanes 0..31 (k=0..7)  = rows of tile 2T   (emb in e=0..4)
// A-fragment lanes 32..63 (k=8..15)= rows of tile 2T+1 (emb in e=0..4)
// B-frag bfLO: k=0..4 = (x,y,z,-|b|^2/2,1), k>=8 zero  -> C = tile2T   x col
// B-frag bfHI: k=8..12 = same, k<8 zero               -> C = tile2T+1 x col
// ONE full-width ds_read_b128 feeds 4 MFMAs (2 row-tiles x 2 col-tiles).
// C[i][j] = a.b - (|a|^2+|b|^2)/2 = -dist^2/2 ; min dist^2 = -2 max C.
//
// R25: UNROLL-2 AT 256-REG BUDGET. R14's unroll-2 spilled under the
// 128-reg (512,4) cap; at (512,2) the unrolled live set (~190 regs)
// fits. Two independent iteration bodies let the scheduler issue iter
// T+1's MFMAs during iter T's folds — cross-iteration ILP the rolled
// loop denies. Tripwire: k1 WRITE_SIZE blowup = spill -> revert.

typedef _Float16 half8 __attribute__((ext_vector_type(8)));
typedef float floatx16 __attribute__((ext_vector_type(16)));

constexpr int B_ = 64;
constexpr int N_ = 2048;
constexpr int NT = N_ / 32;        // 64 row-tiles
constexpr int NPAIR = NT / 2;      // 32 packed tile-pairs
constexpr int BLOCK = 512;         // 8 waves
constexpr int WPB = 8;
constexpr int BFRAGS = 2;          // col-tiles per wave
constexpr int IBLK = NT / (WPB * BFRAGS);   // 4 blocks along col-tile axis
constexpr int NBLK = IBLK * B_ * 2;         // 512 partials
constexpr int RBLOCK = 256;

__global__ __launch_bounds__(BLOCK, 2) void chamfer_mfma_kernel(
    const float* __restrict__ p, const float* __restrict__ q,
    float* __restrict__ partials)
{
    __shared__ half8 Aarr[N_ + 64];       // 33 KB: +1 pad tile for prefetch
    __shared__ float wsum[WPB];

    const int dir = blockIdx.z;            // 0: A=q,B=p ; 1: A=p,B=q
    const int b   = blockIdx.y;
    const float4* rowsA = (const float4*)((dir == 0 ? q : p) + (size_t)b * N_ * 4);
    const float4* colsB = (const float4*)((dir == 0 ? p : q) + (size_t)b * N_ * 4);

    // Build the A-embedding table: Aarr[j] = (x,y,z,1,-|a|^2/2,0,0,0).
    for (int j = threadIdx.x; j < N_; j += BLOCK) {
        float4 v = rowsA[j];
        _Float16 x = (_Float16)v.y, y = (_Float16)v.z, z = (_Float16)v.w;
        float xf = (float)x, yf = (float)y, zf = (float)z;
        float sq = fmaf(xf, xf, fmaf(yf, yf, zf * zf));
        half8 lo;
        lo[0] = x; lo[1] = y; lo[2] = z; lo[3] = (_Float16)1.0f;
        lo[4] = (_Float16)(-0.5f * sq);
        lo[5] = (_Float16)0.0f; lo[6] = (_Float16)0.0f; lo[7] = (_Float16)0.0f;
        Aarr[j] = lo;
    }

    // Per-wave B fragments: col-tiles 2W, 2W+1; each as LO (k=0..7 lanes)
    // and HI (k=8..15 lanes) variants.
    const int lane = threadIdx.x & 63;
    const int wid  = threadIdx.x >> 6;
    const int W    = blockIdx.x * WPB + wid;
    half8 bfLO[BFRAGS], bfHI[BFRAGS];
#pragma unroll
    for (int t = 0; t < BFRAGS; ++t) {
        float4 v = colsB[(W * BFRAGS + t) * 32 + (lane & 31)];
        _Float16 x = (_Float16)v.y, y = (_Float16)v.z, z = (_Float16)v.w;
        float xf = (float)x, yf = (float)y, zf = (float)z;
        float sq = fmaf(xf, xf, fmaf(yf, yf, zf * zf));
#pragma unroll
        for (int e = 0; e < 8; ++e) { bfLO[t][e] = (_Float16)0.0f; bfHI[t][e] = (_Float16)0.0f; }
        if (lane < 32) {
            bfLO[t][0] = x; bfLO[t][1] = y; bfLO[t][2] = z;
            bfLO[t][3] = (_Float16)(-0.5f * sq);
            bfLO[t][4] = (_Float16)1.0f;
        } else {
            bfHI[t][0] = x; bfHI[t][1] = y; bfHI[t][2] = z;
            bfHI[t][3] = (_Float16)(-0.5f * sq);
            bfHI[t][4] = (_Float16)1.0f;
        }
    }
    __syncthreads();

    floatx16 zero;
#pragma unroll
    for (int i = 0; i < 16; ++i) zero[i] = 0.0f;

    floatx16 accv0, accv1;
#pragma unroll
    for (int i = 0; i < 16; ++i) { accv0[i] = -3.4e38f; accv1[i] = -3.4e38f; }

    // Pipelined sweep, unrolled x2: branch-free af prefetch (pad tile read
    // at T=31, never folded). Two independent bodies per trip let MFMAs of
    // body B issue during body A's folds.
    half8 af = Aarr[lane];
#pragma unroll 2
    for (int T = 0; T < NPAIR; ++T) {
        half8 afn = Aarr[(T + 1) * 64 + lane];   // branch-free prefetch
        floatx16 Ca0 = __builtin_amdgcn_mfma_f32_32x32x16_f16(af, bfLO[0], zero, 0, 0, 0);
        floatx16 Cb0 = __builtin_amdgcn_mfma_f32_32x32x16_f16(af, bfHI[0], zero, 0, 0, 0);
        floatx16 Ca1 = __builtin_amdgcn_mfma_f32_32x32x16_f16(af, bfLO[1], zero, 0, 0, 0);
        floatx16 Cb1 = __builtin_amdgcn_mfma_f32_32x32x16_f16(af, bfHI[1], zero, 0, 0, 0);
#pragma unroll
        for (int i = 0; i < 16; ++i)
            accv0[i] = fmaxf(fmaxf(Ca0[i], Cb0[i]), accv0[i]);
#pragma unroll
        for (int i = 0; i < 16; ++i)
            accv1[i] = fmaxf(fmaxf(Ca1[i], Cb1[i]), accv1[i]);
        af = afn;
    }

    // Reduce the two 16-element accumulators to scalars (once per wave).
    float cmx0 = accv0[0], cmx1 = accv1[0];
#pragma unroll
    for (int i = 1; i < 16; ++i) {
        cmx0 = fmaxf(cmx0, accv0[i]);
        cmx1 = fmaxf(cmx1, accv1[i]);
    }

    // Combine the two lane-halves (each holds half the rows per column).
    cmx0 = fmaxf(cmx0, __shfl_xor(cmx0, 32, 64));
    cmx1 = fmaxf(cmx1, __shfl_xor(cmx1, 32, 64));

    float local = sqrtf(fmaxf(-2.0f * cmx0, 0.0f) + 1e-16f)
                + sqrtf(fmaxf(-2.0f * cmx1, 0.0f) + 1e-16f);

#pragma unroll
    for (int off = 32; off > 0; off >>= 1)
        local += __shfl_xor(local, off, 64);

    if (lane == 0) wsum[wid] = local;
    __syncthreads();
    if (threadIdx.x == 0) {
        float s = 0.0f;
#pragma unroll
        for (int w = 0; w < WPB; ++w) s += wsum[w];
        // 0.5 chamfer factor * 0.5 lane-dup; plain store, no init needed.
        partials[(blockIdx.z * B_ + blockIdx.y) * IBLK + blockIdx.x] = 0.25f * s;
    }
}

__global__ __launch_bounds__(RBLOCK) void chamfer_reduce_kernel(
    const float* __restrict__ partials, float* __restrict__ out)
{
    float v = partials[threadIdx.x] + partials[threadIdx.x + RBLOCK];
#pragma unroll
    for (int off = 32; off > 0; off >>= 1)
        v += __shfl_xor(v, off, 64);

    __shared__ float wsum[RBLOCK / 64];
    if ((threadIdx.x & 63) == 0) wsum[threadIdx.x >> 6] = v;
    __syncthreads();
    if (threadIdx.x == 0) {
        float s = 0.0f;
#pragma unroll
        for (int w = 0; w < RBLOCK / 64; ++w) s += wsum[w];
        out[0] = s;
    }
}

extern "C" void kernel_launch(void* const* d_in, const int* in_sizes, int n_in,
                              void* d_out, int out_size, void* d_ws, size_t ws_size,
                              hipStream_t stream) {
    const float* p = (const float*)d_in[0];
    const float* q = (const float*)d_in[1];
    float* out = (float*)d_out;
    float* partials = (float*)d_ws;

    dim3 grid(IBLK, B_, 2);                 // 4 x 64 x 2 = 512 blocks
    chamfer_mfma_kernel<<<grid, BLOCK, 0, stream>>>(p, q, partials);
    chamfer_reduce_kernel<<<1, RBLOCK, 0, stream>>>(partials, out);
}